// Round 1
// baseline (303.728 us; speedup 1.0000x reference)
//
#include <hip/hip_runtime.h>
#include <hip/hip_bf16.h>
#include <math.h>

constexpr int NV = 32000;
constexpr int NE = 256;
constexpr int NH = 512;
constexpr int NB = 128;
constexpr int NS = 512;
constexpr int NX = NH + NE;   // 768, LSTM0 input dim
constexpr int NG = 4 * NH;    // 2048 gates

// -------- workspace layout (float offsets) --------
constexpr size_t OFF_ALPHA = 0;                        // NB*NS        = 65536
constexpr size_t OFF_XT    = OFF_ALPHA + (size_t)NB*NS;       // NX*NB = 98304
constexpr size_t OFF_H0T   = OFF_XT    + (size_t)NX*NB;       // 65536
constexpr size_t OFF_H1IT  = OFF_H0T   + (size_t)NH*NB;       // 65536
constexpr size_t OFF_C0T   = OFF_H1IT  + (size_t)NH*NB;       // 65536
constexpr size_t OFF_C1T   = OFF_C0T   + (size_t)NH*NB;       // 65536
constexpr size_t OFF_GT    = OFF_C1T   + (size_t)NH*NB;       // NG*NB = 262144 (also reused as pctx)
constexpr size_t OFF_H0NT  = OFF_GT    + (size_t)NG*NB;       // 65536
constexpr size_t OFF_H1NT  = OFF_H0NT  + (size_t)NH*NB;       // 65536

// d_out layout: pred[128*32000] | new_hidden[2*128*512] | new_cell[2*128*512]
constexpr size_t OUT_HID  = (size_t)NB * NV;          // 4096000
constexpr size_t OUT_CELL = OUT_HID + 2ull * NB * NH; // 4227072

__device__ inline float sigf(float x) { return 1.0f / (1.0f + expf(-x)); }

// -------- transpose hidden/cell into [h][b] --------
__global__ __launch_bounds__(256) void transpose_hc(
    const float* __restrict__ hidden, const float* __restrict__ cell,
    float* __restrict__ h0T, float* __restrict__ h1T,
    float* __restrict__ c0T, float* __restrict__ c1T) {
  int idx = blockIdx.x * 256 + threadIdx.x;   // 4*65536 total
  int which = idx >> 16, r = idx & 65535;
  int b = r >> 9, h = r & 511;
  const float* src = (which < 2) ? hidden : cell;
  float v = src[(size_t)(which & 1) * NB * NH + (size_t)b * NH + h];
  float* dst = (which == 0) ? h0T : (which == 1) ? h1T : (which == 2) ? c0T : c1T;
  dst[(size_t)h * NB + b] = v;
}

// -------- attention logits: one wave per (b,s) --------
__global__ __launch_bounds__(256) void attn_logits(
    const float* __restrict__ enc, const float* __restrict__ h0,
    const float* __restrict__ attn_w, const float* __restrict__ attn_b,
    float* __restrict__ logits) {
  const int wave = threadIdx.x >> 6, lane = threadIdx.x & 63;
  const int idx = blockIdx.x * 4 + wave;   // [0, B*S)
  const int b = idx & (NB - 1);
  const int s = idx >> 7;
  const float* e = enc + ((size_t)s * NB + b) * NH;
  const float* h = h0 + (size_t)b * NH;
  float acc = 0.f;
#pragma unroll
  for (int j = 0; j < 8; ++j) {
    int k = j * 64 + lane;
    acc += e[k] * attn_w[k];
    acc += h[k] * attn_w[NH + k];
  }
#pragma unroll
  for (int off = 32; off; off >>= 1) acc += __shfl_xor(acc, off);
  if (lane == 0) logits[(size_t)b * NS + s] = acc + attn_b[0];
}

// -------- softmax over s, per b (in place) --------
__global__ __launch_bounds__(256) void softmax_rows(float* __restrict__ lg) {
  const int b = blockIdx.x, tid = threadIdx.x;
  float v0 = lg[(size_t)b * NS + tid];
  float v1 = lg[(size_t)b * NS + 256 + tid];
  float m = fmaxf(v0, v1);
#pragma unroll
  for (int off = 32; off; off >>= 1) m = fmaxf(m, __shfl_xor(m, off));
  __shared__ float red[4];
  int w = tid >> 6, l = tid & 63;
  if (l == 0) red[w] = m;
  __syncthreads();
  m = fmaxf(fmaxf(red[0], red[1]), fmaxf(red[2], red[3]));
  float e0 = expf(v0 - m), e1 = expf(v1 - m);
  float sum = e0 + e1;
#pragma unroll
  for (int off = 32; off; off >>= 1) sum += __shfl_xor(sum, off);
  __syncthreads();
  __shared__ float red2[4];
  if (l == 0) red2[w] = sum;
  __syncthreads();
  sum = red2[0] + red2[1] + red2[2] + red2[3];
  float inv = 1.0f / sum;
  lg[(size_t)b * NS + tid] = e0 * inv;
  lg[(size_t)b * NS + 256 + tid] = e1 * inv;
}

// -------- partial context: grid = b(128) x hc(2) x sc(2) --------
__global__ __launch_bounds__(256) void context_partial(
    const float* __restrict__ enc, const float* __restrict__ alpha,
    float* __restrict__ pctx) {
  const int bx = blockIdx.x;
  const int b = bx >> 2, hc = (bx >> 1) & 1, sc = bx & 1;
  const int tid = threadIdx.x;
  const int h = hc * 256 + tid;
  __shared__ float sal[256];
  sal[tid] = alpha[(size_t)b * NS + sc * 256 + tid];
  __syncthreads();
  float acc = 0.f;
  const float* e = enc + ((size_t)(sc * 256) * NB + b) * NH + h;
#pragma unroll 4
  for (int s = 0; s < 256; ++s)
    acc += sal[s] * e[(size_t)s * NB * NH];
  pctx[(size_t)sc * (NH * NB) + (size_t)h * NB + b] = acc;
}

// -------- combine context halves + gather embedding into xT[k][b] --------
__global__ __launch_bounds__(256) void finish_x(
    const float* __restrict__ pctx, const float* __restrict__ emb,
    const int* __restrict__ dec, float* __restrict__ xT) {
  int idx = blockIdx.x * 256 + threadIdx.x;   // NX*NB = 98304
  int k = idx >> 7, b = idx & 127;
  if (k < NH) {
    xT[idx] = pctx[idx] + pctx[(size_t)NH * NB + idx];
  } else {
    xT[idx] = emb[(size_t)dec[b] * NE + (k - NH)];
  }
}

// -------- LSTM gates GEMM: outT[n][b] = A1T·W1 + A2T·W2 + b1 + b2 --------
__global__ __launch_bounds__(256) void gemm_gates(
    const float* __restrict__ A1T, const float* __restrict__ W1, int K1len,
    const float* __restrict__ A2T, const float* __restrict__ W2, int K2len,
    const float* __restrict__ bias1, const float* __restrict__ bias2,
    float* __restrict__ outT) {
  const int wave = threadIdx.x >> 6, lane = threadIdx.x & 63;
  const int idx = blockIdx.x * 4 + wave;          // [0, NG*2)
  const int n = __builtin_amdgcn_readfirstlane(idx >> 1);
  const int bb = (idx & 1) * 64;
  float acc = bias1[n] + bias2[n];
  const float* w1 = W1 + (size_t)n * K1len;
  for (int k = 0; k < K1len; k += 4) {
    float4 wv = *reinterpret_cast<const float4*>(w1 + k);
    acc += A1T[(size_t)(k + 0) * NB + bb + lane] * wv.x;
    acc += A1T[(size_t)(k + 1) * NB + bb + lane] * wv.y;
    acc += A1T[(size_t)(k + 2) * NB + bb + lane] * wv.z;
    acc += A1T[(size_t)(k + 3) * NB + bb + lane] * wv.w;
  }
  const float* w2 = W2 + (size_t)n * K2len;
  for (int k = 0; k < K2len; k += 4) {
    float4 wv = *reinterpret_cast<const float4*>(w2 + k);
    acc += A2T[(size_t)(k + 0) * NB + bb + lane] * wv.x;
    acc += A2T[(size_t)(k + 1) * NB + bb + lane] * wv.y;
    acc += A2T[(size_t)(k + 2) * NB + bb + lane] * wv.z;
    acc += A2T[(size_t)(k + 3) * NB + bb + lane] * wv.w;
  }
  outT[(size_t)n * NB + bb + lane] = acc;
}

// -------- LSTM pointwise --------
__global__ __launch_bounds__(256) void lstm_point(
    const float* __restrict__ gT, const float* __restrict__ cT,
    float* __restrict__ h_out, float* __restrict__ c_out,
    float* __restrict__ hT_out) {
  int idx = blockIdx.x * 256 + threadIdx.x;   // NB*NH
  int b = idx & 127, h = idx >> 7;
  float ig = gT[(size_t)(0 * NH + h) * NB + b];
  float fg = gT[(size_t)(1 * NH + h) * NB + b];
  float gg = gT[(size_t)(2 * NH + h) * NB + b];
  float og = gT[(size_t)(3 * NH + h) * NB + b];
  float c = cT[(size_t)h * NB + b];
  float c2 = sigf(fg) * c + sigf(ig) * tanhf(gg);
  float h2 = sigf(og) * tanhf(c2);
  c_out[(size_t)b * NH + h] = c2;
  h_out[(size_t)b * NH + h] = h2;
  hT_out[(size_t)h * NB + b] = h2;
}

// -------- FC: out[b][n] = h1·fc_w[n] + fc_b; wave = 8 n x 128 b --------
__global__ __launch_bounds__(256) void gemm_fc(
    const float* __restrict__ AT, const float* __restrict__ W,
    const float* __restrict__ bias, float* __restrict__ out) {
  const int wave = threadIdx.x >> 6, lane = threadIdx.x & 63;
  const int n0 = __builtin_amdgcn_readfirstlane((blockIdx.x * 4 + wave) * 8);
  const float* w = W + (size_t)n0 * NH;
  float acc0[8], acc1[8];
#pragma unroll
  for (int j = 0; j < 8; ++j) { acc0[j] = 0.f; acc1[j] = 0.f; }
  for (int k = 0; k < NH; k += 4) {
    float a00 = AT[(size_t)(k + 0) * NB + lane];
    float a01 = AT[(size_t)(k + 1) * NB + lane];
    float a02 = AT[(size_t)(k + 2) * NB + lane];
    float a03 = AT[(size_t)(k + 3) * NB + lane];
    float a10 = AT[(size_t)(k + 0) * NB + 64 + lane];
    float a11 = AT[(size_t)(k + 1) * NB + 64 + lane];
    float a12 = AT[(size_t)(k + 2) * NB + 64 + lane];
    float a13 = AT[(size_t)(k + 3) * NB + 64 + lane];
#pragma unroll
    for (int j = 0; j < 8; ++j) {
      float4 wv = *reinterpret_cast<const float4*>(w + (size_t)j * NH + k);
      acc0[j] += a00 * wv.x + a01 * wv.y + a02 * wv.z + a03 * wv.w;
      acc1[j] += a10 * wv.x + a11 * wv.y + a12 * wv.z + a13 * wv.w;
    }
  }
#pragma unroll
  for (int q = 0; q < 2; ++q) {
    float4 bv = *reinterpret_cast<const float4*>(bias + n0 + q * 4);
    float4 o0, o1;
    o0.x = acc0[q * 4 + 0] + bv.x; o0.y = acc0[q * 4 + 1] + bv.y;
    o0.z = acc0[q * 4 + 2] + bv.z; o0.w = acc0[q * 4 + 3] + bv.w;
    o1.x = acc1[q * 4 + 0] + bv.x; o1.y = acc1[q * 4 + 1] + bv.y;
    o1.z = acc1[q * 4 + 2] + bv.z; o1.w = acc1[q * 4 + 3] + bv.w;
    *reinterpret_cast<float4*>(&out[(size_t)lane * NV + n0 + q * 4]) = o0;
    *reinterpret_cast<float4*>(&out[(size_t)(64 + lane) * NV + n0 + q * 4]) = o1;
  }
}

extern "C" void kernel_launch(void* const* d_in, const int* in_sizes, int n_in,
                              void* d_out, int out_size, void* d_ws, size_t ws_size,
                              hipStream_t stream) {
  const int*   dec    = (const int*)d_in[0];
  const float* hidden = (const float*)d_in[1];
  const float* cell   = (const float*)d_in[2];
  const float* enc    = (const float*)d_in[3];
  const float* emb    = (const float*)d_in[4];
  const float* attn_w = (const float*)d_in[5];
  const float* attn_b = (const float*)d_in[6];
  const float* w_ih0  = (const float*)d_in[7];
  const float* w_hh0  = (const float*)d_in[8];
  const float* b_ih0  = (const float*)d_in[9];
  const float* b_hh0  = (const float*)d_in[10];
  const float* w_ih1  = (const float*)d_in[11];
  const float* w_hh1  = (const float*)d_in[12];
  const float* b_ih1  = (const float*)d_in[13];
  const float* b_hh1  = (const float*)d_in[14];
  const float* fc_w   = (const float*)d_in[15];
  const float* fc_b   = (const float*)d_in[16];
  float* out = (float*)d_out;
  float* ws  = (float*)d_ws;

  float* alpha = ws + OFF_ALPHA;
  float* xT    = ws + OFF_XT;
  float* h0T   = ws + OFF_H0T;
  float* h1iT  = ws + OFF_H1IT;
  float* c0T   = ws + OFF_C0T;
  float* c1T   = ws + OFF_C1T;
  float* gT    = ws + OFF_GT;
  float* h0nT  = ws + OFF_H0NT;
  float* h1nT  = ws + OFF_H1NT;

  transpose_hc<<<1024, 256, 0, stream>>>(hidden, cell, h0T, h1iT, c0T, c1T);
  attn_logits<<<(NB * NS) / 4, 256, 0, stream>>>(enc, hidden, attn_w, attn_b, alpha);
  softmax_rows<<<NB, 256, 0, stream>>>(alpha);
  context_partial<<<NB * 4, 256, 0, stream>>>(enc, alpha, gT /*pctx scratch*/);
  finish_x<<<(NX * NB) / 256, 256, 0, stream>>>(gT, emb, dec, xT);
  gemm_gates<<<(NG * 2) / 4, 256, 0, stream>>>(xT, w_ih0, NX, h0T, w_hh0, NH,
                                               b_ih0, b_hh0, gT);
  lstm_point<<<(NB * NH) / 256, 256, 0, stream>>>(gT, c0T, out + OUT_HID,
                                                  out + OUT_CELL, h0nT);
  gemm_gates<<<(NG * 2) / 4, 256, 0, stream>>>(h0nT, w_ih1, NH, h1iT, w_hh1, NH,
                                               b_ih1, b_hh1, gT);
  lstm_point<<<(NB * NH) / 256, 256, 0, stream>>>(gT, c1T, out + OUT_HID + (size_t)NB * NH,
                                                  out + OUT_CELL + (size_t)NB * NH, h1nT);
  gemm_fc<<<NV / 8 / 4, 256, 0, stream>>>(h1nT, fc_w, fc_b, out);
}

// Round 2
// 262.308 us; speedup vs baseline: 1.1579x; 1.1579x over previous
//
#include <hip/hip_runtime.h>
#include <hip/hip_bf16.h>
#include <math.h>

constexpr int NV = 32000;
constexpr int NE = 256;
constexpr int NH = 512;
constexpr int NB = 128;
constexpr int NS = 512;
constexpr int NX = NH + NE;   // 768, LSTM0 input dim
constexpr int NG = 4 * NH;    // 2048 gates

typedef __attribute__((ext_vector_type(8))) short short8;   // bf16x8 frag
typedef __attribute__((ext_vector_type(4))) float f32x4;

// -------- workspace layout (float offsets) --------
constexpr size_t OFF_ALPHA = 0;                               // NB*NS = 65536
constexpr size_t OFF_XT    = OFF_ALPHA + (size_t)NB*NS;       // NX*NB = 98304
constexpr size_t OFF_H0T   = OFF_XT    + (size_t)NX*NB;       // 65536
constexpr size_t OFF_H1IT  = OFF_H0T   + (size_t)NH*NB;       // 65536
constexpr size_t OFF_C0T   = OFF_H1IT  + (size_t)NH*NB;       // 65536
constexpr size_t OFF_C1T   = OFF_C0T   + (size_t)NH*NB;       // 65536
constexpr size_t OFF_GT    = OFF_C1T   + (size_t)NH*NB;       // NG*NB = 262144 (also reused as pctx)
constexpr size_t OFF_H0NT  = OFF_GT    + (size_t)NG*NB;       // 65536
constexpr size_t OFF_HBF   = OFF_H0NT  + (size_t)NH*NB;       // 65536 floats reused as bf16 [128][512]

// d_out layout: pred[128*32000] | new_hidden[2*128*512] | new_cell[2*128*512]
constexpr size_t OUT_HID  = (size_t)NB * NV;          // 4096000
constexpr size_t OUT_CELL = OUT_HID + 2ull * NB * NH; // 4227072

__device__ inline float sigf(float x) { return 1.0f / (1.0f + expf(-x)); }
__device__ inline short bf16s(float x) {
  __hip_bfloat16 h = __float2bfloat16(x);
  return *reinterpret_cast<short*>(&h);
}

// -------- transpose hidden/cell into [h][b] --------
__global__ __launch_bounds__(256) void transpose_hc(
    const float* __restrict__ hidden, const float* __restrict__ cell,
    float* __restrict__ h0T, float* __restrict__ h1T,
    float* __restrict__ c0T, float* __restrict__ c1T) {
  int idx = blockIdx.x * 256 + threadIdx.x;   // 4*65536 total
  int which = idx >> 16, r = idx & 65535;
  int b = r >> 9, h = r & 511;
  const float* src = (which < 2) ? hidden : cell;
  float v = src[(size_t)(which & 1) * NB * NH + (size_t)b * NH + h];
  float* dst = (which == 0) ? h0T : (which == 1) ? h1T : (which == 2) ? c0T : c1T;
  dst[(size_t)h * NB + b] = v;
}

// -------- attention logits: one wave per (b,s) --------
__global__ __launch_bounds__(256) void attn_logits(
    const float* __restrict__ enc, const float* __restrict__ h0,
    const float* __restrict__ attn_w, const float* __restrict__ attn_b,
    float* __restrict__ logits) {
  const int wave = threadIdx.x >> 6, lane = threadIdx.x & 63;
  const int idx = blockIdx.x * 4 + wave;   // [0, B*S)
  const int b = idx & (NB - 1);
  const int s = idx >> 7;
  const float* e = enc + ((size_t)s * NB + b) * NH;
  const float* h = h0 + (size_t)b * NH;
  float acc = 0.f;
#pragma unroll
  for (int j = 0; j < 8; ++j) {
    int k = j * 64 + lane;
    acc += e[k] * attn_w[k];
    acc += h[k] * attn_w[NH + k];
  }
#pragma unroll
  for (int off = 32; off; off >>= 1) acc += __shfl_xor(acc, off);
  if (lane == 0) logits[(size_t)b * NS + s] = acc + attn_b[0];
}

// -------- softmax over s, per b (in place) --------
__global__ __launch_bounds__(256) void softmax_rows(float* __restrict__ lg) {
  const int b = blockIdx.x, tid = threadIdx.x;
  float v0 = lg[(size_t)b * NS + tid];
  float v1 = lg[(size_t)b * NS + 256 + tid];
  float m = fmaxf(v0, v1);
#pragma unroll
  for (int off = 32; off; off >>= 1) m = fmaxf(m, __shfl_xor(m, off));
  __shared__ float red[4];
  int w = tid >> 6, l = tid & 63;
  if (l == 0) red[w] = m;
  __syncthreads();
  m = fmaxf(fmaxf(red[0], red[1]), fmaxf(red[2], red[3]));
  float e0 = expf(v0 - m), e1 = expf(v1 - m);
  float sum = e0 + e1;
#pragma unroll
  for (int off = 32; off; off >>= 1) sum += __shfl_xor(sum, off);
  __syncthreads();
  __shared__ float red2[4];
  if (l == 0) red2[w] = sum;
  __syncthreads();
  sum = red2[0] + red2[1] + red2[2] + red2[3];
  float inv = 1.0f / sum;
  lg[(size_t)b * NS + tid] = e0 * inv;
  lg[(size_t)b * NS + 256 + tid] = e1 * inv;
}

// -------- partial context: grid = b(128) x hc(2) x sc(2) --------
__global__ __launch_bounds__(256) void context_partial(
    const float* __restrict__ enc, const float* __restrict__ alpha,
    float* __restrict__ pctx) {
  const int bx = blockIdx.x;
  const int b = bx >> 2, hc = (bx >> 1) & 1, sc = bx & 1;
  const int tid = threadIdx.x;
  const int h = hc * 256 + tid;
  __shared__ float sal[256];
  sal[tid] = alpha[(size_t)b * NS + sc * 256 + tid];
  __syncthreads();
  float acc = 0.f;
  const float* e = enc + ((size_t)(sc * 256) * NB + b) * NH + h;
#pragma unroll 4
  for (int s = 0; s < 256; ++s)
    acc += sal[s] * e[(size_t)s * NB * NH];
  pctx[(size_t)sc * (NH * NB) + (size_t)h * NB + b] = acc;
}

// -------- combine context halves + gather embedding into xT[k][b] --------
__global__ __launch_bounds__(256) void finish_x(
    const float* __restrict__ pctx, const float* __restrict__ emb,
    const int* __restrict__ dec, float* __restrict__ xT) {
  int idx = blockIdx.x * 256 + threadIdx.x;   // NX*NB = 98304
  int k = idx >> 7, b = idx & 127;
  if (k < NH) {
    xT[idx] = pctx[idx] + pctx[(size_t)NH * NB + idx];
  } else {
    xT[idx] = emb[(size_t)dec[b] * NE + (k - NH)];
  }
}

// -------- LSTM gates GEMM: outT[n][b] = A1T·W1 + A2T·W2 + b1 + b2 --------
__global__ __launch_bounds__(256) void gemm_gates(
    const float* __restrict__ A1T, const float* __restrict__ W1, int K1len,
    const float* __restrict__ A2T, const float* __restrict__ W2, int K2len,
    const float* __restrict__ bias1, const float* __restrict__ bias2,
    float* __restrict__ outT) {
  const int wave = threadIdx.x >> 6, lane = threadIdx.x & 63;
  const int idx = blockIdx.x * 4 + wave;          // [0, NG*2)
  const int n = __builtin_amdgcn_readfirstlane(idx >> 1);
  const int bb = (idx & 1) * 64;
  float acc = bias1[n] + bias2[n];
  const float* w1 = W1 + (size_t)n * K1len;
  for (int k = 0; k < K1len; k += 4) {
    float4 wv = *reinterpret_cast<const float4*>(w1 + k);
    acc += A1T[(size_t)(k + 0) * NB + bb + lane] * wv.x;
    acc += A1T[(size_t)(k + 1) * NB + bb + lane] * wv.y;
    acc += A1T[(size_t)(k + 2) * NB + bb + lane] * wv.z;
    acc += A1T[(size_t)(k + 3) * NB + bb + lane] * wv.w;
  }
  const float* w2 = W2 + (size_t)n * K2len;
  for (int k = 0; k < K2len; k += 4) {
    float4 wv = *reinterpret_cast<const float4*>(w2 + k);
    acc += A2T[(size_t)(k + 0) * NB + bb + lane] * wv.x;
    acc += A2T[(size_t)(k + 1) * NB + bb + lane] * wv.y;
    acc += A2T[(size_t)(k + 2) * NB + bb + lane] * wv.z;
    acc += A2T[(size_t)(k + 3) * NB + bb + lane] * wv.w;
  }
  outT[(size_t)n * NB + bb + lane] = acc;
}

// -------- LSTM pointwise --------
__global__ __launch_bounds__(256) void lstm_point(
    const float* __restrict__ gT, const float* __restrict__ cT,
    float* __restrict__ h_out, float* __restrict__ c_out,
    float* __restrict__ hT_out, __hip_bfloat16* __restrict__ hbf_out) {
  int idx = blockIdx.x * 256 + threadIdx.x;   // NB*NH
  int b = idx & 127, h = idx >> 7;
  float ig = gT[(size_t)(0 * NH + h) * NB + b];
  float fg = gT[(size_t)(1 * NH + h) * NB + b];
  float gg = gT[(size_t)(2 * NH + h) * NB + b];
  float og = gT[(size_t)(3 * NH + h) * NB + b];
  float c = cT[(size_t)h * NB + b];
  float c2 = sigf(fg) * c + sigf(ig) * tanhf(gg);
  float h2 = sigf(og) * tanhf(c2);
  c_out[(size_t)b * NH + h] = c2;
  h_out[(size_t)b * NH + h] = h2;
  if (hT_out)  hT_out[(size_t)h * NB + b] = h2;
  if (hbf_out) hbf_out[(size_t)b * NH + h] = __float2bfloat16(h2);
}

// -------- FC via MFMA: out[b][n] = h1·fc_w[n]^T + fc_b --------
// wave = 128(M) x 16(N) strip; A = bf16 [128][512], W = f32 [32000][512]
__global__ __launch_bounds__(256) void gemm_fc_mfma(
    const __hip_bfloat16* __restrict__ Abf, const float* __restrict__ W,
    const float* __restrict__ bias, float* __restrict__ out) {
  const int wave = threadIdx.x >> 6, lane = threadIdx.x & 63;
  const int n0 = (blockIdx.x * 4 + wave) * 16;
  const int l15 = lane & 15, lhi = lane >> 4;
  const float* wrow = W + (size_t)(n0 + l15) * NH + lhi * 8;
  const __hip_bfloat16* arow = Abf + (size_t)l15 * NH + lhi * 8;
  f32x4 acc[8] = {};
  for (int ks = 0; ks < 16; ++ks) {
    const int k0 = ks * 32;
    f32x4 w0 = *reinterpret_cast<const f32x4*>(wrow + k0);
    f32x4 w1 = *reinterpret_cast<const f32x4*>(wrow + k0 + 4);
    short8 bfrag;
    bfrag[0] = bf16s(w0.x); bfrag[1] = bf16s(w0.y);
    bfrag[2] = bf16s(w0.z); bfrag[3] = bf16s(w0.w);
    bfrag[4] = bf16s(w1.x); bfrag[5] = bf16s(w1.y);
    bfrag[6] = bf16s(w1.z); bfrag[7] = bf16s(w1.w);
#pragma unroll
    for (int m = 0; m < 8; ++m) {
      short8 afrag = *reinterpret_cast<const short8*>(arow + (size_t)m * 16 * NH + k0);
      acc[m] = __builtin_amdgcn_mfma_f32_16x16x32_bf16(afrag, bfrag, acc[m], 0, 0, 0);
    }
  }
  const float bv = bias[n0 + l15];
#pragma unroll
  for (int m = 0; m < 8; ++m)
#pragma unroll
    for (int r = 0; r < 4; ++r)
      out[(size_t)(m * 16 + lhi * 4 + r) * NV + n0 + l15] = acc[m][r] + bv;
}

extern "C" void kernel_launch(void* const* d_in, const int* in_sizes, int n_in,
                              void* d_out, int out_size, void* d_ws, size_t ws_size,
                              hipStream_t stream) {
  const int*   dec    = (const int*)d_in[0];
  const float* hidden = (const float*)d_in[1];
  const float* cell   = (const float*)d_in[2];
  const float* enc    = (const float*)d_in[3];
  const float* emb    = (const float*)d_in[4];
  const float* attn_w = (const float*)d_in[5];
  const float* attn_b = (const float*)d_in[6];
  const float* w_ih0  = (const float*)d_in[7];
  const float* w_hh0  = (const float*)d_in[8];
  const float* b_ih0  = (const float*)d_in[9];
  const float* b_hh0  = (const float*)d_in[10];
  const float* w_ih1  = (const float*)d_in[11];
  const float* w_hh1  = (const float*)d_in[12];
  const float* b_ih1  = (const float*)d_in[13];
  const float* b_hh1  = (const float*)d_in[14];
  const float* fc_w   = (const float*)d_in[15];
  const float* fc_b   = (const float*)d_in[16];
  float* out = (float*)d_out;
  float* ws  = (float*)d_ws;

  float* alpha = ws + OFF_ALPHA;
  float* xT    = ws + OFF_XT;
  float* h0T   = ws + OFF_H0T;
  float* h1iT  = ws + OFF_H1IT;
  float* c0T   = ws + OFF_C0T;
  float* c1T   = ws + OFF_C1T;
  float* gT    = ws + OFF_GT;
  float* h0nT  = ws + OFF_H0NT;
  __hip_bfloat16* hbf = (__hip_bfloat16*)(ws + OFF_HBF);

  transpose_hc<<<1024, 256, 0, stream>>>(hidden, cell, h0T, h1iT, c0T, c1T);
  attn_logits<<<(NB * NS) / 4, 256, 0, stream>>>(enc, hidden, attn_w, attn_b, alpha);
  softmax_rows<<<NB, 256, 0, stream>>>(alpha);
  context_partial<<<NB * 4, 256, 0, stream>>>(enc, alpha, gT /*pctx scratch*/);
  finish_x<<<(NX * NB) / 256, 256, 0, stream>>>(gT, emb, dec, xT);
  gemm_gates<<<(NG * 2) / 4, 256, 0, stream>>>(xT, w_ih0, NX, h0T, w_hh0, NH,
                                               b_ih0, b_hh0, gT);
  lstm_point<<<(NB * NH) / 256, 256, 0, stream>>>(gT, c0T, out + OUT_HID,
                                                  out + OUT_CELL, h0nT, nullptr);
  gemm_gates<<<(NG * 2) / 4, 256, 0, stream>>>(h0nT, w_ih1, NH, h1iT, w_hh1, NH,
                                               b_ih1, b_hh1, gT);
  lstm_point<<<(NB * NH) / 256, 256, 0, stream>>>(gT, c1T, out + OUT_HID + (size_t)NB * NH,
                                                  out + OUT_CELL + (size_t)NB * NH,
                                                  nullptr, hbf);
  gemm_fc_mfma<<<NV / 64, 256, 0, stream>>>(hbf, fc_w, fc_b, out);
}

// Round 3
// 135.641 us; speedup vs baseline: 2.2392x; 1.9338x over previous
//
#include <hip/hip_runtime.h>
#include <hip/hip_bf16.h>
#include <math.h>

constexpr int NV = 32000;
constexpr int NE = 256;
constexpr int NH = 512;
constexpr int NB = 128;
constexpr int NS = 512;
constexpr int NX = NH + NE;   // 768, LSTM0 input dim
constexpr int NG = 4 * NH;    // 2048 gates

typedef __attribute__((ext_vector_type(8))) short short8;   // bf16x8 frag
typedef __attribute__((ext_vector_type(4))) float f32x4;

// -------- workspace layout (float offsets) --------
constexpr size_t OFF_ALPHA = 0;                      // 65536
constexpr size_t OFF_XBF   = OFF_ALPHA + 65536;      // 49152 (bf16 [128][768])
constexpr size_t OFF_H0BF  = OFF_XBF   + 49152;      // 32768 (bf16 [128][512])
constexpr size_t OFF_H1BF  = OFF_H0BF  + 32768;      // 32768
constexpr size_t OFF_H0NBF = OFF_H1BF  + 32768;      // 32768
constexpr size_t OFF_H1NBF = OFF_H0NBF + 32768;      // 32768
constexpr size_t OFF_G1    = OFF_H1NBF + 32768;      // 262144 (f32 [128][2048])
constexpr size_t OFF_G2    = OFF_G1    + 262144;     // 262144

// d_out layout: pred[128*32000] | new_hidden[2*128*512] | new_cell[2*128*512]
constexpr size_t OUT_HID  = (size_t)NB * NV;          // 4096000
constexpr size_t OUT_CELL = OUT_HID + 2ull * NB * NH; // 4227072

__device__ inline float sigf(float x) { return 1.0f / (1.0f + expf(-x)); }
__device__ inline short bf16s(float x) {
  __hip_bfloat16 h = __float2bfloat16(x);
  return *reinterpret_cast<short*>(&h);
}

// -------- convert prev hidden (both layers) to bf16 [b][h] --------
__global__ __launch_bounds__(256) void hconv(
    const float* __restrict__ hidden,
    __hip_bfloat16* __restrict__ h0bf, __hip_bfloat16* __restrict__ h1bf) {
  int idx = blockIdx.x * 256 + threadIdx.x;   // 2*65536
  float v = hidden[idx];
  if (idx < NB * NH) h0bf[idx] = __float2bfloat16(v);
  else               h1bf[idx - NB * NH] = __float2bfloat16(v);
}

// -------- attention logits: one wave per (b,s) --------
__global__ __launch_bounds__(256) void attn_logits(
    const float* __restrict__ enc, const float* __restrict__ h0,
    const float* __restrict__ attn_w, const float* __restrict__ attn_b,
    float* __restrict__ logits) {
  const int wave = threadIdx.x >> 6, lane = threadIdx.x & 63;
  const int idx = blockIdx.x * 4 + wave;   // [0, B*S)
  const int b = idx & (NB - 1);
  const int s = idx >> 7;
  const float* e = enc + ((size_t)s * NB + b) * NH;
  const float* h = h0 + (size_t)b * NH;
  float acc = 0.f;
#pragma unroll
  for (int j = 0; j < 8; ++j) {
    int k = j * 64 + lane;
    acc += e[k] * attn_w[k];
    acc += h[k] * attn_w[NH + k];
  }
#pragma unroll
  for (int off = 32; off; off >>= 1) acc += __shfl_xor(acc, off);
  if (lane == 0) logits[(size_t)b * NS + s] = acc + attn_b[0];
}

// -------- softmax over s, per b (in place) --------
__global__ __launch_bounds__(256) void softmax_rows(float* __restrict__ lg) {
  const int b = blockIdx.x, tid = threadIdx.x;
  float v0 = lg[(size_t)b * NS + tid];
  float v1 = lg[(size_t)b * NS + 256 + tid];
  float m = fmaxf(v0, v1);
#pragma unroll
  for (int off = 32; off; off >>= 1) m = fmaxf(m, __shfl_xor(m, off));
  __shared__ float red[4];
  int w = tid >> 6, l = tid & 63;
  if (l == 0) red[w] = m;
  __syncthreads();
  m = fmaxf(fmaxf(red[0], red[1]), fmaxf(red[2], red[3]));
  float e0 = expf(v0 - m), e1 = expf(v1 - m);
  float sum = e0 + e1;
#pragma unroll
  for (int off = 32; off; off >>= 1) sum += __shfl_xor(sum, off);
  __syncthreads();
  __shared__ float red2[4];
  if (l == 0) red2[w] = sum;
  __syncthreads();
  sum = red2[0] + red2[1] + red2[2] + red2[3];
  float inv = 1.0f / sum;
  lg[(size_t)b * NS + tid] = e0 * inv;
  lg[(size_t)b * NS + 256 + tid] = e1 * inv;
}

// -------- context + embedding gather -> xbf bf16 [128][768] --------
// grid: 128 b x 3 chunks (0/1: context halves, 2: embedding)
__global__ __launch_bounds__(256) void ctx_emb(
    const float* __restrict__ enc, const float* __restrict__ alpha,
    const float* __restrict__ emb, const int* __restrict__ dec,
    __hip_bfloat16* __restrict__ xbf) {
  const int b = blockIdx.x / 3, chunk = blockIdx.x % 3;
  const int tid = threadIdx.x;
  if (chunk < 2) {
    __shared__ float sal[NS];
    sal[tid] = alpha[(size_t)b * NS + tid];
    sal[tid + 256] = alpha[(size_t)b * NS + 256 + tid];
    __syncthreads();
    const int h = chunk * 256 + tid;
    const float* e = enc + (size_t)b * NH + h;
    float acc = 0.f;
#pragma unroll 8
    for (int s = 0; s < NS; ++s)
      acc += sal[s] * e[(size_t)s * NB * NH];
    xbf[(size_t)b * NX + h] = __float2bfloat16(acc);
  } else {
    xbf[(size_t)b * NX + NH + tid] =
        __float2bfloat16(emb[(size_t)dec[b] * NE + tid]);
  }
}

// -------- LSTM gate GEMM pair via MFMA: g[b][n] = A[b][:]·W[n][:] --------
// blockIdx.y selects the (A,W,K,g) pair. wave = one 16x16 output tile.
__global__ __launch_bounds__(256) void gates_pair(
    const __hip_bfloat16* __restrict__ A0, const float* __restrict__ W0,
    int K0, float* __restrict__ gout0,
    const __hip_bfloat16* __restrict__ A1, const float* __restrict__ W1,
    int K1, float* __restrict__ gout1) {
  const __hip_bfloat16* A; const float* W; float* g; int K;
  if (blockIdx.y == 0) { A = A0; W = W0; K = K0; g = gout0; }
  else                 { A = A1; W = W1; K = K1; g = gout1; }
  const int wv = __builtin_amdgcn_readfirstlane(blockIdx.x * 4 + (threadIdx.x >> 6));
  const int lane = threadIdx.x & 63;
  const int l15 = lane & 15, lhi = lane >> 4;
  const int ntile = wv >> 3, mtile = wv & 7;          // 128 n-tiles x 8 m-tiles
  const int n0 = ntile * 16;
  const float* wrow = W + (size_t)(n0 + l15) * K + lhi * 8;
  const __hip_bfloat16* arow = A + (size_t)(mtile * 16 + l15) * K + lhi * 8;
  f32x4 acc = {};
#pragma unroll 4
  for (int k0 = 0; k0 < K; k0 += 32) {
    f32x4 w0 = *reinterpret_cast<const f32x4*>(wrow + k0);
    f32x4 w1 = *reinterpret_cast<const f32x4*>(wrow + k0 + 4);
    short8 bfrag;
    bfrag[0] = bf16s(w0.x); bfrag[1] = bf16s(w0.y);
    bfrag[2] = bf16s(w0.z); bfrag[3] = bf16s(w0.w);
    bfrag[4] = bf16s(w1.x); bfrag[5] = bf16s(w1.y);
    bfrag[6] = bf16s(w1.z); bfrag[7] = bf16s(w1.w);
    short8 afrag = *reinterpret_cast<const short8*>(arow + k0);
    acc = __builtin_amdgcn_mfma_f32_16x16x32_bf16(afrag, bfrag, acc, 0, 0, 0);
  }
#pragma unroll
  for (int r = 0; r < 4; ++r)
    g[(size_t)(mtile * 16 + lhi * 4 + r) * NG + n0 + l15] = acc[r];
}

// -------- LSTM pointwise: sum partials + biases, activations --------
__global__ __launch_bounds__(256) void lstm_point(
    const float* __restrict__ g1, const float* __restrict__ g2,
    const float* __restrict__ b_ih, const float* __restrict__ b_hh,
    const float* __restrict__ c_in,
    float* __restrict__ h_out, float* __restrict__ c_out,
    __hip_bfloat16* __restrict__ hbf_out) {
  int idx = blockIdx.x * 256 + threadIdx.x;   // NB*NH
  int b = idx >> 9, h = idx & 511;
  size_t base = (size_t)b * NG;
  float ig = g1[base + 0 * NH + h] + g2[base + 0 * NH + h] + b_ih[0 * NH + h] + b_hh[0 * NH + h];
  float fg = g1[base + 1 * NH + h] + g2[base + 1 * NH + h] + b_ih[1 * NH + h] + b_hh[1 * NH + h];
  float gg = g1[base + 2 * NH + h] + g2[base + 2 * NH + h] + b_ih[2 * NH + h] + b_hh[2 * NH + h];
  float og = g1[base + 3 * NH + h] + g2[base + 3 * NH + h] + b_ih[3 * NH + h] + b_hh[3 * NH + h];
  float c = c_in[idx];
  float c2 = sigf(fg) * c + sigf(ig) * tanhf(gg);
  float h2 = sigf(og) * tanhf(c2);
  c_out[idx] = c2;
  h_out[idx] = h2;
  hbf_out[idx] = __float2bfloat16(h2);
}

// -------- FC via MFMA: out[b][n] = h1·fc_w[n]^T + fc_b --------
// wave = 128(M) x 16(N) strip; A = bf16 [128][512], W = f32 [32000][512]
__global__ __launch_bounds__(256) void gemm_fc_mfma(
    const __hip_bfloat16* __restrict__ Abf, const float* __restrict__ W,
    const float* __restrict__ bias, float* __restrict__ out) {
  const int wave = threadIdx.x >> 6, lane = threadIdx.x & 63;
  const int n0 = (blockIdx.x * 4 + wave) * 16;
  const int l15 = lane & 15, lhi = lane >> 4;
  const float* wrow = W + (size_t)(n0 + l15) * NH + lhi * 8;
  const __hip_bfloat16* arow = Abf + (size_t)l15 * NH + lhi * 8;
  f32x4 acc[8] = {};
  for (int ks = 0; ks < 16; ++ks) {
    const int k0 = ks * 32;
    f32x4 w0 = *reinterpret_cast<const f32x4*>(wrow + k0);
    f32x4 w1 = *reinterpret_cast<const f32x4*>(wrow + k0 + 4);
    short8 bfrag;
    bfrag[0] = bf16s(w0.x); bfrag[1] = bf16s(w0.y);
    bfrag[2] = bf16s(w0.z); bfrag[3] = bf16s(w0.w);
    bfrag[4] = bf16s(w1.x); bfrag[5] = bf16s(w1.y);
    bfrag[6] = bf16s(w1.z); bfrag[7] = bf16s(w1.w);
#pragma unroll
    for (int m = 0; m < 8; ++m) {
      short8 afrag = *reinterpret_cast<const short8*>(arow + (size_t)m * 16 * NH + k0);
      acc[m] = __builtin_amdgcn_mfma_f32_16x16x32_bf16(afrag, bfrag, acc[m], 0, 0, 0);
    }
  }
  const float bv = bias[n0 + l15];
#pragma unroll
  for (int m = 0; m < 8; ++m)
#pragma unroll
    for (int r = 0; r < 4; ++r)
      out[(size_t)(m * 16 + lhi * 4 + r) * NV + n0 + l15] = acc[m][r] + bv;
}

extern "C" void kernel_launch(void* const* d_in, const int* in_sizes, int n_in,
                              void* d_out, int out_size, void* d_ws, size_t ws_size,
                              hipStream_t stream) {
  const int*   dec    = (const int*)d_in[0];
  const float* hidden = (const float*)d_in[1];
  const float* cell   = (const float*)d_in[2];
  const float* enc    = (const float*)d_in[3];
  const float* emb    = (const float*)d_in[4];
  const float* attn_w = (const float*)d_in[5];
  const float* attn_b = (const float*)d_in[6];
  const float* w_ih0  = (const float*)d_in[7];
  const float* w_hh0  = (const float*)d_in[8];
  const float* b_ih0  = (const float*)d_in[9];
  const float* b_hh0  = (const float*)d_in[10];
  const float* w_ih1  = (const float*)d_in[11];
  const float* w_hh1  = (const float*)d_in[12];
  const float* b_ih1  = (const float*)d_in[13];
  const float* b_hh1  = (const float*)d_in[14];
  const float* fc_w   = (const float*)d_in[15];
  const float* fc_b   = (const float*)d_in[16];
  float* out = (float*)d_out;
  float* ws  = (float*)d_ws;

  float* alpha = ws + OFF_ALPHA;
  __hip_bfloat16* xbf   = (__hip_bfloat16*)(ws + OFF_XBF);
  __hip_bfloat16* h0bf  = (__hip_bfloat16*)(ws + OFF_H0BF);
  __hip_bfloat16* h1bf  = (__hip_bfloat16*)(ws + OFF_H1BF);
  __hip_bfloat16* h0nbf = (__hip_bfloat16*)(ws + OFF_H0NBF);
  __hip_bfloat16* h1nbf = (__hip_bfloat16*)(ws + OFF_H1NBF);
  float* g1 = ws + OFF_G1;
  float* g2 = ws + OFF_G2;

  hconv<<<512, 256, 0, stream>>>(hidden, h0bf, h1bf);
  attn_logits<<<(NB * NS) / 4, 256, 0, stream>>>(enc, hidden, attn_w, attn_b, alpha);
  softmax_rows<<<NB, 256, 0, stream>>>(alpha);
  ctx_emb<<<NB * 3, 256, 0, stream>>>(enc, alpha, emb, dec, xbf);
  gates_pair<<<dim3(256, 2), 256, 0, stream>>>(xbf, w_ih0, NX, g1,
                                               h0bf, w_hh0, NH, g2);
  lstm_point<<<256, 256, 0, stream>>>(g1, g2, b_ih0, b_hh0, cell,
                                      out + OUT_HID, out + OUT_CELL, h0nbf);
  gates_pair<<<dim3(256, 2), 256, 0, stream>>>(h0nbf, w_ih1, NH, g1,
                                               h1bf, w_hh1, NH, g2);
  lstm_point<<<256, 256, 0, stream>>>(g1, g2, b_ih1, b_hh1, cell + NB * NH,
                                      out + OUT_HID + (size_t)NB * NH,
                                      out + OUT_CELL + (size_t)NB * NH, h1nbf);
  gemm_fc_mfma<<<NV / 64, 256, 0, stream>>>(h1nbf, fc_w, fc_b, out);
}

// Round 4
// 112.490 us; speedup vs baseline: 2.7001x; 1.2058x over previous
//
#include <hip/hip_runtime.h>
#include <hip/hip_bf16.h>
#include <math.h>

constexpr int NV = 32000;
constexpr int NE = 256;
constexpr int NH = 512;
constexpr int NB = 128;
constexpr int NS = 512;
constexpr int NX = NH + NE;   // 768, LSTM0 input dim
constexpr int NG = 4 * NH;    // 2048 gates
constexpr int NSC = 8;        // s-chunks for attention partials

typedef __attribute__((ext_vector_type(8))) short short8;   // bf16x8 frag
typedef __attribute__((ext_vector_type(4))) float f32x4;

// -------- workspace layout (float offsets) --------
constexpr size_t OFF_PCTX  = 0;                                   // 128*8*512 = 524288
constexpr size_t OFF_PML   = OFF_PCTX  + (size_t)NB*NSC*NH;       // 128*8*2   = 2048
constexpr size_t OFF_XBF   = OFF_PML   + (size_t)NB*NSC*2;        // 49152 (bf16 [128][768])
constexpr size_t OFF_H0BF  = OFF_XBF   + 49152;                   // 32768 (bf16 [128][512])
constexpr size_t OFF_H1BF  = OFF_H0BF  + 32768;                   // 32768
constexpr size_t OFF_H0NBF = OFF_H1BF  + 32768;                   // 32768
constexpr size_t OFF_H1NBF = OFF_H0NBF + 32768;                   // 32768
constexpr size_t OFF_G1    = OFF_H1NBF + 32768;                   // 262144 (f32 [128][2048])
constexpr size_t OFF_G2    = OFF_G1    + 262144;                  // 262144

// d_out layout: pred[128*32000] | new_hidden[2*128*512] | new_cell[2*128*512]
constexpr size_t OUT_HID  = (size_t)NB * NV;          // 4096000
constexpr size_t OUT_CELL = OUT_HID + 2ull * NB * NH; // 4227072

__device__ inline float sigf(float x) { return 1.0f / (1.0f + expf(-x)); }
__device__ inline short bf16s(float x) {
  __hip_bfloat16 h = __float2bfloat16(x);
  return *reinterpret_cast<short*>(&h);
}

// -------- convert prev hidden (both layers) to bf16 [b][h] --------
__global__ __launch_bounds__(256) void hconv(
    const float* __restrict__ hidden,
    __hip_bfloat16* __restrict__ h0bf, __hip_bfloat16* __restrict__ h1bf) {
  int idx = blockIdx.x * 256 + threadIdx.x;   // 2*65536
  float v = hidden[idx];
  if (idx < NB * NH) h0bf[idx] = __float2bfloat16(v);
  else               h1bf[idx - NB * NH] = __float2bfloat16(v);
}

// -------- one-pass online-softmax attention partial --------
// grid (NSC, NB); wave w handles s = sc*64 + i*4 + w, i<16.
// Note: the w_hid·h0 + attn_b logit term is constant per b and cancels in
// softmax, so it is omitted.
__global__ __launch_bounds__(256) void attn_partial(
    const float* __restrict__ enc, const float* __restrict__ attn_w,
    float* __restrict__ pctx, float* __restrict__ pml) {
  const int sc = blockIdx.x, b = blockIdx.y;
  const int wv = threadIdx.x >> 6, lane = threadIdx.x & 63;
  float wenc[8];
#pragma unroll
  for (int j = 0; j < 8; ++j) wenc[j] = attn_w[j * 64 + lane];
  float m = -INFINITY, l = 0.f, acc[8] = {};
  const float* base = enc + ((size_t)(sc * 64 + wv) * NB + b) * NH + lane;
  for (int i = 0; i < 16; ++i) {
    const float* erow = base + (size_t)i * 4 * NB * NH;
    float ev[8];
#pragma unroll
    for (int j = 0; j < 8; ++j) ev[j] = erow[j * 64];
    float dot = 0.f;
#pragma unroll
    for (int j = 0; j < 8; ++j) dot += ev[j] * wenc[j];
#pragma unroll
    for (int off = 32; off; off >>= 1) dot += __shfl_xor(dot, off);
    float mn = fmaxf(m, dot);
    float scale = expf(m - mn);
    float p = expf(dot - mn);
    l = l * scale + p;
#pragma unroll
    for (int j = 0; j < 8; ++j) acc[j] = acc[j] * scale + p * ev[j];
    m = mn;
  }
  // merge the 4 waves via LDS
  __shared__ float sm[4], sl[4], sacc[4][NH];
  if (lane == 0) { sm[wv] = m; sl[wv] = l; }
#pragma unroll
  for (int j = 0; j < 8; ++j) sacc[wv][j * 64 + lane] = acc[j];
  __syncthreads();
  const float M = fmaxf(fmaxf(sm[0], sm[1]), fmaxf(sm[2], sm[3]));
  const float e0 = expf(sm[0] - M), e1 = expf(sm[1] - M),
              e2 = expf(sm[2] - M), e3 = expf(sm[3] - M);
  const int t = threadIdx.x;
  float* outc = pctx + ((size_t)b * NSC + sc) * NH;
#pragma unroll
  for (int q = 0; q < 2; ++q) {
    int h = q * 256 + t;
    outc[h] = sacc[0][h] * e0 + sacc[1][h] * e1 + sacc[2][h] * e2 + sacc[3][h] * e3;
  }
  if (t == 0) {
    pml[((size_t)b * NSC + sc) * 2 + 0] = M;
    pml[((size_t)b * NSC + sc) * 2 + 1] = sl[0] * e0 + sl[1] * e1 + sl[2] * e2 + sl[3] * e3;
  }
}

// -------- merge chunk partials, normalize, emit bf16 x (+embedding) --------
__global__ __launch_bounds__(256) void attn_finish(
    const float* __restrict__ pctx, const float* __restrict__ pml,
    const float* __restrict__ emb, const int* __restrict__ dec,
    __hip_bfloat16* __restrict__ xbf) {
  const int b = blockIdx.x, t = threadIdx.x;
  float ms[NSC];
  float M = -INFINITY;
#pragma unroll
  for (int sc = 0; sc < NSC; ++sc) {
    ms[sc] = pml[((size_t)b * NSC + sc) * 2 + 0];
    M = fmaxf(M, ms[sc]);
  }
  float L = 0.f, es[NSC];
#pragma unroll
  for (int sc = 0; sc < NSC; ++sc) {
    es[sc] = expf(ms[sc] - M);
    L += pml[((size_t)b * NSC + sc) * 2 + 1] * es[sc];
  }
  const float invL = 1.f / L;
#pragma unroll
  for (int q = 0; q < 2; ++q) {
    int h = q * 256 + t;
    float v = 0.f;
#pragma unroll
    for (int sc = 0; sc < NSC; ++sc)
      v += pctx[((size_t)b * NSC + sc) * NH + h] * es[sc];
    xbf[(size_t)b * NX + h] = __float2bfloat16(v * invL);
  }
  xbf[(size_t)b * NX + NH + t] = __float2bfloat16(emb[(size_t)dec[b] * NE + t]);
}

// -------- LSTM gate GEMM pair via MFMA: g[b][n] = A[b][:]·W[n][:] --------
// blockIdx.y selects the (A,W,K,g) pair. wave = one 16x16 output tile.
__global__ __launch_bounds__(256) void gates_pair(
    const __hip_bfloat16* __restrict__ A0, const float* __restrict__ W0,
    int K0, float* __restrict__ gout0,
    const __hip_bfloat16* __restrict__ A1, const float* __restrict__ W1,
    int K1, float* __restrict__ gout1) {
  const __hip_bfloat16* A; const float* W; float* g; int K;
  if (blockIdx.y == 0) { A = A0; W = W0; K = K0; g = gout0; }
  else                 { A = A1; W = W1; K = K1; g = gout1; }
  const int wv = __builtin_amdgcn_readfirstlane(blockIdx.x * 4 + (threadIdx.x >> 6));
  const int lane = threadIdx.x & 63;
  const int l15 = lane & 15, lhi = lane >> 4;
  const int ntile = wv >> 3, mtile = wv & 7;          // 128 n-tiles x 8 m-tiles
  const int n0 = ntile * 16;
  const float* wrow = W + (size_t)(n0 + l15) * K + lhi * 8;
  const __hip_bfloat16* arow = A + (size_t)(mtile * 16 + l15) * K + lhi * 8;
  f32x4 acc = {};
#pragma unroll 4
  for (int k0 = 0; k0 < K; k0 += 32) {
    f32x4 w0 = *reinterpret_cast<const f32x4*>(wrow + k0);
    f32x4 w1 = *reinterpret_cast<const f32x4*>(wrow + k0 + 4);
    short8 bfrag;
    bfrag[0] = bf16s(w0.x); bfrag[1] = bf16s(w0.y);
    bfrag[2] = bf16s(w0.z); bfrag[3] = bf16s(w0.w);
    bfrag[4] = bf16s(w1.x); bfrag[5] = bf16s(w1.y);
    bfrag[6] = bf16s(w1.z); bfrag[7] = bf16s(w1.w);
    short8 afrag = *reinterpret_cast<const short8*>(arow + k0);
    acc = __builtin_amdgcn_mfma_f32_16x16x32_bf16(afrag, bfrag, acc, 0, 0, 0);
  }
#pragma unroll
  for (int r = 0; r < 4; ++r)
    g[(size_t)(mtile * 16 + lhi * 4 + r) * NG + n0 + l15] = acc[r];
}

// -------- LSTM pointwise: sum partials + biases, activations --------
__global__ __launch_bounds__(256) void lstm_point(
    const float* __restrict__ g1, const float* __restrict__ g2,
    const float* __restrict__ b_ih, const float* __restrict__ b_hh,
    const float* __restrict__ c_in,
    float* __restrict__ h_out, float* __restrict__ c_out,
    __hip_bfloat16* __restrict__ hbf_out) {
  int idx = blockIdx.x * 256 + threadIdx.x;   // NB*NH
  int b = idx >> 9, h = idx & 511;
  size_t base = (size_t)b * NG;
  float ig = g1[base + 0 * NH + h] + g2[base + 0 * NH + h] + b_ih[0 * NH + h] + b_hh[0 * NH + h];
  float fg = g1[base + 1 * NH + h] + g2[base + 1 * NH + h] + b_ih[1 * NH + h] + b_hh[1 * NH + h];
  float gg = g1[base + 2 * NH + h] + g2[base + 2 * NH + h] + b_ih[2 * NH + h] + b_hh[2 * NH + h];
  float og = g1[base + 3 * NH + h] + g2[base + 3 * NH + h] + b_ih[3 * NH + h] + b_hh[3 * NH + h];
  float c = c_in[idx];
  float c2 = sigf(fg) * c + sigf(ig) * tanhf(gg);
  float h2 = sigf(og) * tanhf(c2);
  c_out[idx] = c2;
  h_out[idx] = h2;
  hbf_out[idx] = __float2bfloat16(h2);
}

// -------- FC via MFMA: out[b][n] = h1·fc_w[n]^T + fc_b --------
// wave = 128(M) x 16(N) strip; A = bf16 [128][512], W = f32 [32000][512]
__global__ __launch_bounds__(256) void gemm_fc_mfma(
    const __hip_bfloat16* __restrict__ Abf, const float* __restrict__ W,
    const float* __restrict__ bias, float* __restrict__ out) {
  const int wave = threadIdx.x >> 6, lane = threadIdx.x & 63;
  const int n0 = (blockIdx.x * 4 + wave) * 16;
  const int l15 = lane & 15, lhi = lane >> 4;
  const float* wrow = W + (size_t)(n0 + l15) * NH + lhi * 8;
  const __hip_bfloat16* arow = Abf + (size_t)l15 * NH + lhi * 8;
  f32x4 acc[8] = {};
  for (int ks = 0; ks < 16; ++ks) {
    const int k0 = ks * 32;
    f32x4 w0 = *reinterpret_cast<const f32x4*>(wrow + k0);
    f32x4 w1 = *reinterpret_cast<const f32x4*>(wrow + k0 + 4);
    short8 bfrag;
    bfrag[0] = bf16s(w0.x); bfrag[1] = bf16s(w0.y);
    bfrag[2] = bf16s(w0.z); bfrag[3] = bf16s(w0.w);
    bfrag[4] = bf16s(w1.x); bfrag[5] = bf16s(w1.y);
    bfrag[6] = bf16s(w1.z); bfrag[7] = bf16s(w1.w);
#pragma unroll
    for (int m = 0; m < 8; ++m) {
      short8 afrag = *reinterpret_cast<const short8*>(arow + (size_t)m * 16 * NH + k0);
      acc[m] = __builtin_amdgcn_mfma_f32_16x16x32_bf16(afrag, bfrag, acc[m], 0, 0, 0);
    }
  }
  const float bv = bias[n0 + l15];
#pragma unroll
  for (int m = 0; m < 8; ++m)
#pragma unroll
    for (int r = 0; r < 4; ++r)
      out[(size_t)(m * 16 + lhi * 4 + r) * NV + n0 + l15] = acc[m][r] + bv;
}

extern "C" void kernel_launch(void* const* d_in, const int* in_sizes, int n_in,
                              void* d_out, int out_size, void* d_ws, size_t ws_size,
                              hipStream_t stream) {
  const int*   dec    = (const int*)d_in[0];
  const float* hidden = (const float*)d_in[1];
  const float* cell   = (const float*)d_in[2];
  const float* enc    = (const float*)d_in[3];
  const float* emb    = (const float*)d_in[4];
  const float* attn_w = (const float*)d_in[5];
  const float* attn_b = (const float*)d_in[6];
  const float* w_ih0  = (const float*)d_in[7];
  const float* w_hh0  = (const float*)d_in[8];
  const float* b_ih0  = (const float*)d_in[9];
  const float* b_hh0  = (const float*)d_in[10];
  const float* w_ih1  = (const float*)d_in[11];
  const float* w_hh1  = (const float*)d_in[12];
  const float* b_ih1  = (const float*)d_in[13];
  const float* b_hh1  = (const float*)d_in[14];
  const float* fc_w   = (const float*)d_in[15];
  const float* fc_b   = (const float*)d_in[16];
  float* out = (float*)d_out;
  float* ws  = (float*)d_ws;

  float* pctx = ws + OFF_PCTX;
  float* pml  = ws + OFF_PML;
  __hip_bfloat16* xbf   = (__hip_bfloat16*)(ws + OFF_XBF);
  __hip_bfloat16* h0bf  = (__hip_bfloat16*)(ws + OFF_H0BF);
  __hip_bfloat16* h1bf  = (__hip_bfloat16*)(ws + OFF_H1BF);
  __hip_bfloat16* h0nbf = (__hip_bfloat16*)(ws + OFF_H0NBF);
  __hip_bfloat16* h1nbf = (__hip_bfloat16*)(ws + OFF_H1NBF);
  float* g1 = ws + OFF_G1;
  float* g2 = ws + OFF_G2;

  hconv<<<512, 256, 0, stream>>>(hidden, h0bf, h1bf);
  attn_partial<<<dim3(NSC, NB), 256, 0, stream>>>(enc, attn_w, pctx, pml);
  attn_finish<<<NB, 256, 0, stream>>>(pctx, pml, emb, dec, xbf);
  gates_pair<<<dim3(256, 2), 256, 0, stream>>>(xbf, w_ih0, NX, g1,
                                               h0bf, w_hh0, NH, g2);
  lstm_point<<<256, 256, 0, stream>>>(g1, g2, b_ih0, b_hh0, cell,
                                      out + OUT_HID, out + OUT_CELL, h0nbf);
  gates_pair<<<dim3(256, 2), 256, 0, stream>>>(h0nbf, w_ih1, NH, g1,
                                               h1bf, w_hh1, NH, g2);
  lstm_point<<<256, 256, 0, stream>>>(g1, g2, b_ih1, b_hh1, cell + NB * NH,
                                      out + OUT_HID + (size_t)NB * NH,
                                      out + OUT_CELL + (size_t)NB * NH, h1nbf);
  gemm_fc_mfma<<<NV / 64, 256, 0, stream>>>(h1nbf, fc_w, fc_b, out);
}

// Round 5
// 107.738 us; speedup vs baseline: 2.8191x; 1.0441x over previous
//
#include <hip/hip_runtime.h>
#include <hip/hip_bf16.h>
#include <math.h>

constexpr int NV = 32000;
constexpr int NE = 256;
constexpr int NH = 512;
constexpr int NB = 128;
constexpr int NS = 512;
constexpr int NX = NH + NE;   // 768, LSTM0 input dim
constexpr int NG = 4 * NH;    // 2048 gates
constexpr int NSC = 8;        // s-chunks for attention partials

typedef __attribute__((ext_vector_type(8))) short short8;   // bf16x8 frag
typedef __attribute__((ext_vector_type(4))) float f32x4;

// -------- workspace layout (float offsets) --------
constexpr size_t OFF_PCTX  = 0;                                   // 524288
constexpr size_t OFF_PML   = OFF_PCTX  + (size_t)NB*NSC*NH;       // 2048
constexpr size_t OFF_XBF   = OFF_PML   + (size_t)NB*NSC*2;        // 49152 (bf16 [128][768])
constexpr size_t OFF_H0NBF = OFF_XBF   + 49152;                   // 32768 (bf16 [128][512])
constexpr size_t OFF_H1NBF = OFF_H0NBF + 32768;                   // 32768

// d_out layout: pred[128*32000] | new_hidden[2*128*512] | new_cell[2*128*512]
constexpr size_t OUT_HID  = (size_t)NB * NV;          // 4096000
constexpr size_t OUT_CELL = OUT_HID + 2ull * NB * NH; // 4227072

__device__ inline float sigf(float x) { return 1.0f / (1.0f + expf(-x)); }
__device__ inline short bf16s(float x) {
  __hip_bfloat16 h = __float2bfloat16(x);
  return *reinterpret_cast<short*>(&h);
}

// -------- one-pass online-softmax attention partial --------
// grid (NSC, NB); wave w handles s = sc*64 + i*4 + w, i<16.
// w_hid·h0 + attn_b is constant per b and cancels in softmax -> omitted.
__global__ __launch_bounds__(256) void attn_partial(
    const float* __restrict__ enc, const float* __restrict__ attn_w,
    float* __restrict__ pctx, float* __restrict__ pml) {
  const int sc = blockIdx.x, b = blockIdx.y;
  const int wv = threadIdx.x >> 6, lane = threadIdx.x & 63;
  float wenc[8];
#pragma unroll
  for (int j = 0; j < 8; ++j) wenc[j] = attn_w[j * 64 + lane];
  float m = -INFINITY, l = 0.f, acc[8] = {};
  const float* base = enc + ((size_t)(sc * 64 + wv) * NB + b) * NH + lane;
  for (int i = 0; i < 16; ++i) {
    const float* erow = base + (size_t)i * 4 * NB * NH;
    float ev[8];
#pragma unroll
    for (int j = 0; j < 8; ++j) ev[j] = erow[j * 64];
    float dot = 0.f;
#pragma unroll
    for (int j = 0; j < 8; ++j) dot += ev[j] * wenc[j];
#pragma unroll
    for (int off = 32; off; off >>= 1) dot += __shfl_xor(dot, off);
    float mn = fmaxf(m, dot);
    float scale = expf(m - mn);
    float p = expf(dot - mn);
    l = l * scale + p;
#pragma unroll
    for (int j = 0; j < 8; ++j) acc[j] = acc[j] * scale + p * ev[j];
    m = mn;
  }
  __shared__ float sm[4], sl[4], sacc[4][NH];
  if (lane == 0) { sm[wv] = m; sl[wv] = l; }
#pragma unroll
  for (int j = 0; j < 8; ++j) sacc[wv][j * 64 + lane] = acc[j];
  __syncthreads();
  const float M = fmaxf(fmaxf(sm[0], sm[1]), fmaxf(sm[2], sm[3]));
  const float e0 = expf(sm[0] - M), e1 = expf(sm[1] - M),
              e2 = expf(sm[2] - M), e3 = expf(sm[3] - M);
  const int t = threadIdx.x;
  float* outc = pctx + ((size_t)b * NSC + sc) * NH;
#pragma unroll
  for (int q = 0; q < 2; ++q) {
    int h = q * 256 + t;
    outc[h] = sacc[0][h] * e0 + sacc[1][h] * e1 + sacc[2][h] * e2 + sacc[3][h] * e3;
  }
  if (t == 0) {
    pml[((size_t)b * NSC + sc) * 2 + 0] = M;
    pml[((size_t)b * NSC + sc) * 2 + 1] = sl[0] * e0 + sl[1] * e1 + sl[2] * e2 + sl[3] * e3;
  }
}

// -------- merge chunk partials, normalize, emit bf16 x (+embedding) --------
__global__ __launch_bounds__(256) void attn_finish(
    const float* __restrict__ pctx, const float* __restrict__ pml,
    const float* __restrict__ emb, const int* __restrict__ dec,
    __hip_bfloat16* __restrict__ xbf) {
  const int b = blockIdx.x, t = threadIdx.x;
  float ms[NSC];
  float M = -INFINITY;
#pragma unroll
  for (int sc = 0; sc < NSC; ++sc) {
    ms[sc] = pml[((size_t)b * NSC + sc) * 2 + 0];
    M = fmaxf(M, ms[sc]);
  }
  float L = 0.f, es[NSC];
#pragma unroll
  for (int sc = 0; sc < NSC; ++sc) {
    es[sc] = expf(ms[sc] - M);
    L += pml[((size_t)b * NSC + sc) * 2 + 1] * es[sc];
  }
  const float invL = 1.f / L;
#pragma unroll
  for (int q = 0; q < 2; ++q) {
    int h = q * 256 + t;
    float v = 0.f;
#pragma unroll
    for (int sc = 0; sc < NSC; ++sc)
      v += pctx[((size_t)b * NSC + sc) * NH + h] * es[sc];
    xbf[(size_t)b * NX + h] = __float2bfloat16(v * invL);
  }
  xbf[(size_t)b * NX + NH + t] = __float2bfloat16(emb[(size_t)dec[b] * NE + t]);
}

// -------- fused LSTM layer: GEMMs (x·Wih + h·Whh) + pointwise in one --------
// grid 256 blocks (8 m-tiles x 32 h16-chunks), 512 threads = 8 waves.
// wave w: gate = w&3, part = w>>2. part0: x(bf16)·W_ih ; part1: h(f32)·W_hh.
__global__ __launch_bounds__(512) void fused_lstm(
    const __hip_bfloat16* __restrict__ Abf, int strideA, int K0,
    const float* __restrict__ Wih,
    const float* __restrict__ hf32, const float* __restrict__ Whh,
    const float* __restrict__ b_ih, const float* __restrict__ b_hh,
    const float* __restrict__ c_in,
    float* __restrict__ h_out, float* __restrict__ c_out,
    __hip_bfloat16* __restrict__ hbf_out) {
  const int wid = threadIdx.x >> 6, lane = threadIdx.x & 63;
  const int gate = wid & 3, part = wid >> 2;
  const int l15 = lane & 15, lhi = lane >> 4;
  const int mtile = blockIdx.x >> 5, h16 = blockIdx.x & 31;
  const int n = gate * NH + h16 * 16 + l15;           // W row
  f32x4 acc = {};
  if (part == 0) {
    const float* wrow = Wih + (size_t)n * K0 + lhi * 8;
    const __hip_bfloat16* arow = Abf + (size_t)(mtile * 16 + l15) * strideA + lhi * 8;
#pragma unroll 4
    for (int k0 = 0; k0 < K0; k0 += 32) {
      f32x4 w0 = *reinterpret_cast<const f32x4*>(wrow + k0);
      f32x4 w1 = *reinterpret_cast<const f32x4*>(wrow + k0 + 4);
      short8 bfrag;
      bfrag[0] = bf16s(w0.x); bfrag[1] = bf16s(w0.y);
      bfrag[2] = bf16s(w0.z); bfrag[3] = bf16s(w0.w);
      bfrag[4] = bf16s(w1.x); bfrag[5] = bf16s(w1.y);
      bfrag[6] = bf16s(w1.z); bfrag[7] = bf16s(w1.w);
      short8 afrag = *reinterpret_cast<const short8*>(arow + k0);
      acc = __builtin_amdgcn_mfma_f32_16x16x32_bf16(afrag, bfrag, acc, 0, 0, 0);
    }
  } else {
    const float* wrow = Whh + (size_t)n * NH + lhi * 8;
    const float* arow = hf32 + (size_t)(mtile * 16 + l15) * NH + lhi * 8;
#pragma unroll 4
    for (int k0 = 0; k0 < NH; k0 += 32) {
      f32x4 w0 = *reinterpret_cast<const f32x4*>(wrow + k0);
      f32x4 w1 = *reinterpret_cast<const f32x4*>(wrow + k0 + 4);
      f32x4 a0 = *reinterpret_cast<const f32x4*>(arow + k0);
      f32x4 a1 = *reinterpret_cast<const f32x4*>(arow + k0 + 4);
      short8 bfrag, afrag;
      bfrag[0] = bf16s(w0.x); bfrag[1] = bf16s(w0.y);
      bfrag[2] = bf16s(w0.z); bfrag[3] = bf16s(w0.w);
      bfrag[4] = bf16s(w1.x); bfrag[5] = bf16s(w1.y);
      bfrag[6] = bf16s(w1.z); bfrag[7] = bf16s(w1.w);
      afrag[0] = bf16s(a0.x); afrag[1] = bf16s(a0.y);
      afrag[2] = bf16s(a0.z); afrag[3] = bf16s(a0.w);
      afrag[4] = bf16s(a1.x); afrag[5] = bf16s(a1.y);
      afrag[6] = bf16s(a1.z); afrag[7] = bf16s(a1.w);
      acc = __builtin_amdgcn_mfma_f32_16x16x32_bf16(afrag, bfrag, acc, 0, 0, 0);
    }
  }
  __shared__ float sg[8][16][17];
#pragma unroll
  for (int r = 0; r < 4; ++r) sg[wid][lhi * 4 + r][l15] = acc[r];
  __syncthreads();
  const int t = threadIdx.x;
  if (t < 256) {
    const int row = t >> 4, col = t & 15;
    const int b = mtile * 16 + row, h = h16 * 16 + col;
    float ig = sg[0][row][col] + sg[4][row][col] + b_ih[0 * NH + h] + b_hh[0 * NH + h];
    float fg = sg[1][row][col] + sg[5][row][col] + b_ih[1 * NH + h] + b_hh[1 * NH + h];
    float gg = sg[2][row][col] + sg[6][row][col] + b_ih[2 * NH + h] + b_hh[2 * NH + h];
    float og = sg[3][row][col] + sg[7][row][col] + b_ih[3 * NH + h] + b_hh[3 * NH + h];
    float c = c_in[(size_t)b * NH + h];
    float c2 = sigf(fg) * c + sigf(ig) * tanhf(gg);
    float h2 = sigf(og) * tanhf(c2);
    c_out[(size_t)b * NH + h] = c2;
    h_out[(size_t)b * NH + h] = h2;
    hbf_out[(size_t)b * NH + h] = __float2bfloat16(h2);
  }
}

// -------- FC via MFMA: out[b][n] = h1·fc_w[n]^T + fc_b --------
// wave = 64(M-half) x 16(N); A = bf16 [128][512], W = f32 [32000][512]
__global__ __launch_bounds__(256) void gemm_fc_mfma(
    const __hip_bfloat16* __restrict__ Abf, const float* __restrict__ W,
    const float* __restrict__ bias, float* __restrict__ out) {
  const int wave = threadIdx.x >> 6, lane = threadIdx.x & 63;
  const int gid = blockIdx.x * 4 + wave;      // 0..3999
  const int n0 = (gid >> 1) * 16, mhalf = gid & 1;
  const int l15 = lane & 15, lhi = lane >> 4;
  const float* wrow = W + (size_t)(n0 + l15) * NH + lhi * 8;
  const __hip_bfloat16* arow = Abf + (size_t)(mhalf * 64 + l15) * NH + lhi * 8;
  f32x4 acc[4] = {};
#pragma unroll 4
  for (int ks = 0; ks < 16; ++ks) {
    const int k0 = ks * 32;
    f32x4 w0 = *reinterpret_cast<const f32x4*>(wrow + k0);
    f32x4 w1 = *reinterpret_cast<const f32x4*>(wrow + k0 + 4);
    short8 bfrag;
    bfrag[0] = bf16s(w0.x); bfrag[1] = bf16s(w0.y);
    bfrag[2] = bf16s(w0.z); bfrag[3] = bf16s(w0.w);
    bfrag[4] = bf16s(w1.x); bfrag[5] = bf16s(w1.y);
    bfrag[6] = bf16s(w1.z); bfrag[7] = bf16s(w1.w);
#pragma unroll
    for (int m = 0; m < 4; ++m) {
      short8 afrag = *reinterpret_cast<const short8*>(arow + (size_t)m * 16 * NH + k0);
      acc[m] = __builtin_amdgcn_mfma_f32_16x16x32_bf16(afrag, bfrag, acc[m], 0, 0, 0);
    }
  }
  const float bv = bias[n0 + l15];
#pragma unroll
  for (int m = 0; m < 4; ++m)
#pragma unroll
    for (int r = 0; r < 4; ++r)
      out[(size_t)(mhalf * 64 + m * 16 + lhi * 4 + r) * NV + n0 + l15] = acc[m][r] + bv;
}

extern "C" void kernel_launch(void* const* d_in, const int* in_sizes, int n_in,
                              void* d_out, int out_size, void* d_ws, size_t ws_size,
                              hipStream_t stream) {
  const int*   dec    = (const int*)d_in[0];
  const float* hidden = (const float*)d_in[1];
  const float* cell   = (const float*)d_in[2];
  const float* enc    = (const float*)d_in[3];
  const float* emb    = (const float*)d_in[4];
  const float* attn_w = (const float*)d_in[5];
  const float* attn_b = (const float*)d_in[6];
  const float* w_ih0  = (const float*)d_in[7];
  const float* w_hh0  = (const float*)d_in[8];
  const float* b_ih0  = (const float*)d_in[9];
  const float* b_hh0  = (const float*)d_in[10];
  const float* w_ih1  = (const float*)d_in[11];
  const float* w_hh1  = (const float*)d_in[12];
  const float* b_ih1  = (const float*)d_in[13];
  const float* b_hh1  = (const float*)d_in[14];
  const float* fc_w   = (const float*)d_in[15];
  const float* fc_b   = (const float*)d_in[16];
  float* out = (float*)d_out;
  float* ws  = (float*)d_ws;

  float* pctx = ws + OFF_PCTX;
  float* pml  = ws + OFF_PML;
  __hip_bfloat16* xbf   = (__hip_bfloat16*)(ws + OFF_XBF);
  __hip_bfloat16* h0nbf = (__hip_bfloat16*)(ws + OFF_H0NBF);
  __hip_bfloat16* h1nbf = (__hip_bfloat16*)(ws + OFF_H1NBF);

  attn_partial<<<dim3(NSC, NB), 256, 0, stream>>>(enc, attn_w, pctx, pml);
  attn_finish<<<NB, 256, 0, stream>>>(pctx, pml, emb, dec, xbf);
  fused_lstm<<<256, 512, 0, stream>>>(xbf, NX, NX, w_ih0, hidden, w_hh0,
                                      b_ih0, b_hh0, cell,
                                      out + OUT_HID, out + OUT_CELL, h0nbf);
  fused_lstm<<<256, 512, 0, stream>>>(h0nbf, NH, NH, w_ih1, hidden + NB * NH, w_hh1,
                                      b_ih1, b_hh1, cell + NB * NH,
                                      out + OUT_HID + (size_t)NB * NH,
                                      out + OUT_CELL + (size_t)NB * NH, h1nbf);
  gemm_fc_mfma<<<1000, 256, 0, stream>>>(h1nbf, fc_w, fc_b, out);
}